// Round 9
// baseline (1178.212 us; speedup 1.0000x reference)
//
#include <hip/hip_runtime.h>
#include <cstdio>

#define B_   256
#define H_   512
#define G4_  2048
#define T_   326
#define OUT_ 9

typedef __attribute__((ext_vector_type(8))) short s16x8;
typedef __attribute__((ext_vector_type(4))) float f32x4;
typedef unsigned long long ull;

__device__ inline unsigned short to_bf16(float f) {
    unsigned int u = __builtin_bit_cast(unsigned int, f);
    unsigned int r = (u + 0x7fffu + ((u >> 16) & 1u)) >> 16;  // RNE
    return (unsigned short)r;
}

__device__ inline float sigmoidf_(float x) { return 1.0f / (1.0f + __expf(-x)); }

__device__ inline float fast_tanh(float x) {
    x = fminf(fmaxf(x, -15.f), 15.f);
    float e = __expf(2.f * x);
    return (e - 1.f) / (e + 1.f);
}

// ---------------- prep kernels ----------------

__global__ void prep_weights(const float* __restrict__ Wih, const float* __restrict__ Whh,
                             const float* __restrict__ bih, const float* __restrict__ bhh,
                             unsigned short* __restrict__ Wc, unsigned short* __restrict__ Wcat,
                             float* __restrict__ bc) {
    int idx = blockIdx.x * 256 + threadIdx.x;      // < 2048*512
    int n = idx >> 9, k = idx & 511;
    float wi = Wih[idx], wh = Whh[idx];
    Wc[idx] = to_bf16(wi + wh);
    Wcat[(n << 10) + k]       = to_bf16(wi);
    Wcat[(n << 10) + 512 + k] = to_bf16(wh);
    if (k == 0) bc[n] = bih[n] + bhh[n];
}

__global__ void prep_w1(const float* __restrict__ W1, unsigned short* __restrict__ W1b) {
    int idx = blockIdx.x * 256 + threadIdx.x;      // < 512*512
    W1b[idx] = to_bf16(W1[idx]);
}

__global__ void prep_w2(const float* __restrict__ W2, unsigned short* __restrict__ W2b) {
    int idx = blockIdx.x * 256 + threadIdx.x;      // < 16*512
    int o = idx >> 9, k = idx & 511;
    W2b[idx] = (o < OUT_) ? to_bf16(W2[o * H_ + k]) : (unsigned short)0;
}

__global__ void prep_x(const float* __restrict__ x, const float* __restrict__ hx0,
                       unsigned short* __restrict__ xcat) {
    int idx = blockIdx.x * 256 + threadIdx.x;      // < 256*512
    int b = idx >> 9, k = idx & 511;
    xcat[(b << 10) + k]       = to_bf16(x[idx]);
    xcat[(b << 10) + 512 + k] = to_bf16(hx0[idx]);
}

// ---------------- step 0 (K=1024, [x|hx0] @ [Wih|Whh]) ----------------
template <int KLEN>
__global__ __launch_bounds__(256) void lstm_step(
    const unsigned short* __restrict__ A,
    const unsigned short* __restrict__ W,
    const float* __restrict__ bc,
    const float* __restrict__ c_in,
    float* __restrict__ c_out,
    unsigned short* __restrict__ h_out) {
    const int lane = threadIdx.x & 63;
    const int wave = threadIdx.x >> 6;
    const int mn = lane & 15, q = lane >> 4;
    const int rt = blockIdx.x & 15;
    const int hb = (blockIdx.x >> 4) * 64 + wave * 16;

    const unsigned short* ap  = A + (size_t)(rt * 16 + mn) * KLEN + q * 8;
    const unsigned short* wp0 = W + (size_t)(0 * H_ + hb + mn) * KLEN + q * 8;
    const unsigned short* wp1 = W + (size_t)(1 * H_ + hb + mn) * KLEN + q * 8;
    const unsigned short* wp2 = W + (size_t)(2 * H_ + hb + mn) * KLEN + q * 8;
    const unsigned short* wp3 = W + (size_t)(3 * H_ + hb + mn) * KLEN + q * 8;

    f32x4 acc0 = {0.f,0.f,0.f,0.f}, acc1 = {0.f,0.f,0.f,0.f};
    f32x4 acc2 = {0.f,0.f,0.f,0.f}, acc3 = {0.f,0.f,0.f,0.f};
#pragma unroll 4
    for (int k0 = 0; k0 < KLEN; k0 += 32) {
        s16x8 a  = *reinterpret_cast<const s16x8*>(ap + k0);
        s16x8 w0 = *reinterpret_cast<const s16x8*>(wp0 + k0);
        s16x8 w1 = *reinterpret_cast<const s16x8*>(wp1 + k0);
        s16x8 w2 = *reinterpret_cast<const s16x8*>(wp2 + k0);
        s16x8 w3 = *reinterpret_cast<const s16x8*>(wp3 + k0);
        acc0 = __builtin_amdgcn_mfma_f32_16x16x32_bf16(a, w0, acc0, 0, 0, 0);
        acc1 = __builtin_amdgcn_mfma_f32_16x16x32_bf16(a, w1, acc1, 0, 0, 0);
        acc2 = __builtin_amdgcn_mfma_f32_16x16x32_bf16(a, w2, acc2, 0, 0, 0);
        acc3 = __builtin_amdgcn_mfma_f32_16x16x32_bf16(a, w3, acc3, 0, 0, 0);
    }

    const int j = hb + mn;
    const float bi = bc[j], bfv = bc[H_ + j], bg = bc[2 * H_ + j], bo = bc[3 * H_ + j];
#pragma unroll
    for (int r = 0; r < 4; ++r) {
        const int row = rt * 16 + q * 4 + r;
        const float iv = sigmoidf_(acc0[r] + bi);
        const float fv = sigmoidf_(acc1[r] + bfv);
        const float gv = fast_tanh(acc2[r] + bg);
        const float ov = sigmoidf_(acc3[r] + bo);
        const float co = c_in[row * H_ + j];
        const float cn = fv * co + iv * gv;
        c_out[row * H_ + j] = cn;
        h_out[row * H_ + j] = to_bf16(ov * fast_tanh(cn));
    }
}

// -------- persistent LSTM (blocks 0..255) + MLP consumers (256..383) --------
// NORMAL launch (R8 proved cooperative launch was the R4/R5/R7 silent-failure
// mechanism). Deadlock safety: LDS 33KB (4 blocks/CU) and VGPR<=~160 (2
// blocks/CU) -> capacity 512 >= 384, so ALL blocks get slots immediately,
// persist WGs are co-resident; consumers never gate persist.
//  PERSIST: verbatim-R3 (verified 733us): 16 groups (g=blockIdx&15, XCD g%8)
//    x 16 WGs, 32 cols/WG, counter barrier; only change: publish ctr at EVERY
//    t (incl. 325) so consumers can proceed; spin still skipped at t=325.
//  CONSUMER: R4's role. j = blockIdx-256 serves XCD j&7 (= g%8 of its items,
//    matching round-robin block->XCD dispatch). Item (t,g): poll ctr[g]>=16t
//    (s_sleep backoff), stage h_t rows [g*16,+16) via the same swizzled path,
//    z = relu(h@W1^T+b1) (4 waves x 8 N-tiles), y = z@W2^T+b2 (wave 0, W2
//    from L2), plain stores to d_out (verified path; no atomics).
__global__ __launch_bounds__(256) void lstm_persist(
    const unsigned short* __restrict__ Wc,   // [2048][512] bf16
    const float* __restrict__ bc,            // [2048]
    const float* __restrict__ c0,            // [256][512] f32 (from step 0)
    unsigned short* __restrict__ h_hist,     // [326][256][512] bf16
    unsigned int* __restrict__ ctr,          // 16 counters, 128B apart
    const unsigned short* __restrict__ W1b,  // [512][512] bf16
    const float* __restrict__ b1,            // [512]
    const unsigned short* __restrict__ W2b,  // [16][512] bf16 (rows 9..15 zero)
    const float* __restrict__ b2,            // [9]
    float* __restrict__ out) {               // [256][326][9] f32
    // LDS overlay: [0,16384) A_lds (both roles);
    // [16384, ...) persist: gate_lds (8448B) | consumer: z_lds (16640B)
    __shared__ ull smem[4128];                   // 33024 B
    unsigned short* A_lds = reinterpret_cast<unsigned short*>(smem);
    float* gate_lds = reinterpret_cast<float*>(reinterpret_cast<char*>(smem) + 16384);
    unsigned short* z_lds = reinterpret_cast<unsigned short*>(reinterpret_cast<char*>(smem) + 16384);
    const int tid = threadIdx.x;
    const int lane = tid & 63, wave = tid >> 6;
    const int mn = lane & 15, q = lane >> 4;

    // swizzled ushort indices (verbatim R3; both roles)
    int a_st[8];
#pragma unroll
    for (int p = 0; p < 8; ++p) {
        const int qi = p * 256 + tid;
        const int row = qi >> 7;                 // 128 qwords per 512-col row
        const int bcol = (qi & 127) * 8;
        a_st[p] = row * 512 + ((bcol ^ ((row & 7) << 4)) >> 1);
    }
    int a_rd[16];
#pragma unroll
    for (int kk = 0; kk < 16; ++kk) {
        const int bcol = kk * 64 + q * 16;
        a_rd[kk] = mn * 512 + ((bcol ^ ((mn & 7) << 4)) >> 1);
    }

    if (blockIdx.x < 256) {
        // ================= PERSIST role (verbatim R3) =================
        const int g  = blockIdx.x & 15;          // group (same XCD: g%8)
        const int jb = (blockIdx.x >> 4) * 32;   // 32 cols per WG
        unsigned int* ctr_g = ctr + g * 32;      // own cacheline per group

        s16x8 breg[2][16];
#pragma unroll
        for (int n = 0; n < 2; ++n) {
            const unsigned short* wp = Wc + (size_t)(wave * H_ + jb + n * 16 + mn) * H_ + q * 8;
#pragma unroll
            for (int kk = 0; kk < 16; ++kk)
                breg[n][kk] = *reinterpret_cast<const s16x8*>(wp + kk * 32);
        }
        const float bcv0 = bc[wave * H_ + jb + mn];
        const float bcv1 = bc[wave * H_ + jb + 16 + mn];

        const int crow = tid >> 4, cc0 = (tid & 15) * 2;
        float c_x = c0[(size_t)(g * 16 + crow) * H_ + jb + cc0];
        float c_y = c0[(size_t)(g * 16 + crow) * H_ + jb + cc0 + 1];

        for (int t = 1; t < T_; ++t) {
            // ---- stage A = h_{t-1} rows [g*16, g*16+16) via sc1 8B loads ----
            const ull* hsrc64 = reinterpret_cast<const ull*>(
                h_hist + (size_t)(t - 1) * (B_ * H_) + (size_t)g * 16 * H_);
            ull vv[8];
#pragma unroll
            for (int p = 0; p < 8; ++p)
                vv[p] = __hip_atomic_load(hsrc64 + p * 256 + tid, __ATOMIC_RELAXED,
                                          __HIP_MEMORY_SCOPE_AGENT);
#pragma unroll
            for (int p = 0; p < 8; ++p)
                *reinterpret_cast<ull*>(&A_lds[a_st[p]]) = vv[p];
            __syncthreads();

            // ---- gates via MFMA (M=16, N=2x16, K=512) ----
            f32x4 acc0 = {0.f,0.f,0.f,0.f}, acc1 = {0.f,0.f,0.f,0.f};
#pragma unroll
            for (int kk = 0; kk < 16; ++kk) {
                s16x8 a = *reinterpret_cast<const s16x8*>(&A_lds[a_rd[kk]]);
                acc0 = __builtin_amdgcn_mfma_f32_16x16x32_bf16(a, breg[0][kk], acc0, 0, 0, 0);
                acc1 = __builtin_amdgcn_mfma_f32_16x16x32_bf16(a, breg[1][kk], acc1, 0, 0, 0);
            }

            // ---- activations -> gate LDS ----
#pragma unroll
            for (int r = 0; r < 4; ++r) {
                float v0 = acc0[r] + bcv0, v1 = acc1[r] + bcv1;
                if (wave == 2) { v0 = fast_tanh(v0); v1 = fast_tanh(v1); }
                else           { v0 = sigmoidf_(v0); v1 = sigmoidf_(v1); }
                gate_lds[(wave * 16 + (q * 4 + r)) * 33 + mn]      = v0;
                gate_lds[(wave * 16 + (q * 4 + r)) * 33 + 16 + mn] = v1;
            }
            __syncthreads();

            // ---- c/h update ----
            {
                float iv0 = gate_lds[(0 * 16 + crow) * 33 + cc0], iv1 = gate_lds[(0 * 16 + crow) * 33 + cc0 + 1];
                float fv0 = gate_lds[(1 * 16 + crow) * 33 + cc0], fv1 = gate_lds[(1 * 16 + crow) * 33 + cc0 + 1];
                float gv0 = gate_lds[(2 * 16 + crow) * 33 + cc0], gv1 = gate_lds[(2 * 16 + crow) * 33 + cc0 + 1];
                float ov0 = gate_lds[(3 * 16 + crow) * 33 + cc0], ov1 = gate_lds[(3 * 16 + crow) * 33 + cc0 + 1];
                c_x = fv0 * c_x + iv0 * gv0;
                c_y = fv1 * c_y + iv1 * gv1;
                unsigned int h0 = to_bf16(ov0 * fast_tanh(c_x));
                unsigned int h1 = to_bf16(ov1 * fast_tanh(c_y));
                unsigned int packed = h0 | (h1 << 16);
                unsigned int* hdst = reinterpret_cast<unsigned int*>(
                    h_hist + (size_t)t * (B_ * H_) + (size_t)(g * 16 + crow) * H_ + jb + cc0);
                __hip_atomic_store(hdst, packed, __ATOMIC_RELAXED, __HIP_MEMORY_SCOPE_AGENT);
            }

            // ---- per-group barrier; publish EVERY step (spin skipped at 325) ----
            __syncthreads();  // emits s_waitcnt vmcnt(0): sc1 h-stores complete
            asm volatile("" ::: "memory");
            if (tid == 0) {
                __hip_atomic_fetch_add(ctr_g, 1u, __ATOMIC_RELAXED, __HIP_MEMORY_SCOPE_AGENT);
                if (t < T_ - 1) {
                    const unsigned int target = 16u * (unsigned int)t;
                    while (__hip_atomic_load(ctr_g, __ATOMIC_RELAXED,
                                             __HIP_MEMORY_SCOPE_AGENT) < target) {
                    }
                }
            }
            asm volatile("" ::: "memory");
            if (t < T_ - 1) __syncthreads();
        }
    } else {
        // ================= MLP consumer role =================
        const int j = blockIdx.x - 256;              // 0..127
        const int xcd = j & 7, mid = j >> 3;         // mid 0..15

        float b1v[8];
#pragma unroll
        for (int nt = 0; nt < 8; ++nt) b1v[nt] = b1[wave * 128 + nt * 16 + mn];
        const float b2v = (mn < OUT_) ? b2[mn] : 0.f;

        // items: i in [0, 652), t = i>>1, g = xcd + 8*(i&1)  (monotone t)
        for (int i = mid; i < 2 * T_; i += 16) {
            const int t = i >> 1;
            const int g = xcd + 8 * (i & 1);

            if (tid == 0) {
                const unsigned int tgt = 16u * (unsigned int)t;
                while (__hip_atomic_load(ctr + g * 32, __ATOMIC_RELAXED,
                                         __HIP_MEMORY_SCOPE_AGENT) < tgt)
                    __builtin_amdgcn_s_sleep(4);
            }
            __syncthreads();

            // ---- stage h_t rows [g*16, g*16+16) (same swizzled path) ----
            const ull* hsrc64 = reinterpret_cast<const ull*>(
                h_hist + (size_t)t * (B_ * H_) + (size_t)g * 16 * H_);
            ull vv[8];
#pragma unroll
            for (int p = 0; p < 8; ++p)
                vv[p] = __hip_atomic_load(hsrc64 + p * 256 + tid, __ATOMIC_RELAXED,
                                          __HIP_MEMORY_SCOPE_AGENT);
#pragma unroll
            for (int p = 0; p < 8; ++p)
                *reinterpret_cast<ull*>(&A_lds[a_st[p]]) = vv[p];
            __syncthreads();

            // ---- z = relu(h @ W1^T + b1): M=16, wave owns 128 z-cols ----
            f32x4 acc[8];
#pragma unroll
            for (int nt = 0; nt < 8; ++nt) acc[nt] = f32x4{0.f,0.f,0.f,0.f};
            for (int kk = 0; kk < 16; ++kk) {
                s16x8 a = *reinterpret_cast<const s16x8*>(&A_lds[a_rd[kk]]);
#pragma unroll
                for (int nt = 0; nt < 8; ++nt) {
                    s16x8 b = *reinterpret_cast<const s16x8*>(
                        W1b + (size_t)(wave * 128 + nt * 16 + mn) * H_ + kk * 32 + q * 8);
                    acc[nt] = __builtin_amdgcn_mfma_f32_16x16x32_bf16(a, b, acc[nt], 0, 0, 0);
                }
            }
#pragma unroll
            for (int nt = 0; nt < 8; ++nt)
#pragma unroll
                for (int r = 0; r < 4; ++r) {
                    float v = acc[nt][r] + b1v[nt];
                    v = v > 0.f ? v : 0.f;
                    z_lds[(q * 4 + r) * 520 + wave * 128 + nt * 16 + mn] = to_bf16(v);
                }
            __syncthreads();

            // ---- y = z @ W2^T + b2 (wave 0), plain stores to out ----
            if (wave == 0) {
                f32x4 y = {0.f,0.f,0.f,0.f};
#pragma unroll 4
                for (int k0 = 0; k0 < 512; k0 += 32) {
                    s16x8 az = *reinterpret_cast<const s16x8*>(&z_lds[mn * 520 + k0 + q * 8]);
                    s16x8 bw = *reinterpret_cast<const s16x8*>(W2b + (size_t)mn * H_ + k0 + q * 8);
                    y = __builtin_amdgcn_mfma_f32_16x16x32_bf16(az, bw, y, 0, 0, 0);
                }
                if (mn < OUT_) {
#pragma unroll
                    for (int r = 0; r < 4; ++r)
                        out[(size_t)(g * 16 + q * 4 + r) * (T_ * OUT_) + t * OUT_ + mn] = y[r] + b2v;
                }
            }
            __syncthreads();
        }
    }
}

// ---------------- host launch ----------------
extern "C" void kernel_launch(void* const* d_in, const int* in_sizes, int n_in,
                              void* d_out, int out_size, void* d_ws, size_t ws_size,
                              hipStream_t stream) {
    (void)in_sizes; (void)n_in; (void)out_size;
    const float* x   = (const float*)d_in[0];
    const float* hx0 = (const float*)d_in[1];
    const float* cx0 = (const float*)d_in[2];
    const float* Wih = (const float*)d_in[3];
    const float* Whh = (const float*)d_in[4];
    const float* bih = (const float*)d_in[5];
    const float* bhh = (const float*)d_in[6];
    const float* W1  = (const float*)d_in[7];
    const float* b1  = (const float*)d_in[8];
    const float* W2  = (const float*)d_in[9];
    const float* b2  = (const float*)d_in[10];
    float* out = (float*)d_out;

    char* p = (char*)d_ws;
    size_t off = 0;
    auto alloc = [&](size_t bytes) {
        void* r = p + off;
        off = (off + bytes + 255) & ~(size_t)255;
        return r;
    };
    unsigned short* Wc     = (unsigned short*)alloc((size_t)G4_ * H_ * 2);
    unsigned short* Wcat   = (unsigned short*)alloc((size_t)G4_ * 1024 * 2);
    unsigned short* W1b    = (unsigned short*)alloc((size_t)H_ * H_ * 2);
    unsigned short* W2b    = (unsigned short*)alloc((size_t)16 * H_ * 2);
    float*          bc     = (float*)alloc((size_t)G4_ * 4);
    unsigned short* xcat   = (unsigned short*)alloc((size_t)B_ * 1024 * 2);
    float*          cbuf   = (float*)alloc((size_t)B_ * H_ * 4);
    unsigned int*   ctr    = (unsigned int*)alloc(4096);
    unsigned short* h_hist = (unsigned short*)alloc((size_t)T_ * B_ * H_ * 2);
    if (off > ws_size) {
        fprintf(stderr, "kernel_launch: ws too small: need %zu have %zu\n", off, ws_size);
        return;
    }

    prep_weights<<<G4_ * H_ / 256, 256, 0, stream>>>(Wih, Whh, bih, bhh, Wc, Wcat, bc);
    prep_w1<<<H_ * H_ / 256, 256, 0, stream>>>(W1, W1b);
    prep_w2<<<16 * H_ / 256, 256, 0, stream>>>(W2, W2b);
    prep_x<<<B_ * H_ / 256, 256, 0, stream>>>(x, hx0, xcat);

    // step 0: K=1024
    lstm_step<1024><<<128, 256, 0, stream>>>(xcat, Wcat, bc, cx0, cbuf, h_hist);

    // zero group counters, then persist (256 WGs) + MLP consumers (128 WGs),
    // NORMAL launch (see kernel comment for co-residency argument)
    hipMemsetAsync(ctr, 0, 4096, stream);
    lstm_persist<<<384, 256, 0, stream>>>(Wc, bc, cbuf, h_hist, ctr,
                                          W1b, b1, W2b, b2, out);
}